// Round 18
// baseline (228.317 us; speedup 1.0000x reference)
//
#include <hip/hip_runtime.h>
#include <math.h>

#define N_ATOMS 50000
#define IN_DIM 128
#define HID 256
#define N_ELEM 4
#define N_IMG 500
#define NNZ 2000000

// forces col-binning (R14: zero global atomics, consumer owns col-windows)
#define CBINS 293        // col >> 9 over 150,016 cols
#define CW 512           // cols per bin (2 KB LDS window)
#define BCAP 8192        // expect 6826 +- 83 (16 sigma headroom)
#define OCAP 4096        // overflow list capacity (expected use: 0)
#define PCH 8192         // producer chunk (entries per block)
#define NBP ((NNZ + PCH - 1) / PCH)   // 245 producer blocks
#define BKB ((N_ATOMS + 255) / 256)   // 196 bucket blocks

typedef __attribute__((ext_vector_type(8))) short bf16x8;   // 8 bf16 = 4 VGPRs
typedef __attribute__((ext_vector_type(4))) float f32x4;    // MFMA C/D frag
typedef __attribute__((ext_vector_type(4))) int   i32x4;    // native vec loads
typedef __attribute__((ext_vector_type(4))) float fv4;      // native vec loads

__device__ __forceinline__ int elem_of(int z) {
    return (z == 1) ? 0 : (z == 6) ? 1 : (z == 8) ? 2 : 3;
}

__device__ __forceinline__ unsigned short f2bf(float f) {   // RNE
    unsigned u = __float_as_uint(f);
    u += 0x7fffu + ((u >> 16) & 1u);
    return (unsigned short)(u >> 16);
}
__device__ __forceinline__ float bf2f(unsigned short u) {
    return __uint_as_float(((unsigned)u) << 16);
}
__device__ __forceinline__ float tanh_fast(float x) {
    float e = __expf(2.f * x);
    return (e - 1.f) / (e + 1.f);
}

// ---------------------------------------------------------------------------
// K1) Weight prep — pre-swizzle into wave-frag order (R9: worth 44us).
//     Block 0 also zeroes counts + binning cursors (consumed next dispatch).
// ---------------------------------------------------------------------------
__global__ __launch_bounds__(256) void prep_weights(
    const float* __restrict__ W0, const float* __restrict__ W1,
    unsigned short* __restrict__ W0s1,   // stage1: Bt[h][d], K=128, KN=4
    unsigned short* __restrict__ W1s2,   // stage2: Bt[h1][h0], K=256, KN=8
    unsigned short* __restrict__ W1s3,   // stage3: Bt[h0][h1], K=256, KN=8
    unsigned short* __restrict__ W0s4,   // stage4: Bt[d][h], K=256, KN=8
    int* __restrict__ counts, int* __restrict__ gcur, int* __restrict__ ocur) {
    if (blockIdx.x == 0) {
        if (threadIdx.x < N_ELEM) counts[threadIdx.x] = 0;
        for (int i = threadIdx.x; i < CBINS; i += 256) gcur[i] = 0;
        if (threadIdx.x == 0) ocur[0] = 0;
    }
    int t = blockIdx.x * 256 + threadIdx.x;
    if (t >= N_ELEM * HID * HID) return;
    int e = t >> 16;
    int rem = t & 65535;
    int k = rem >> 8, n = rem & 255;     // W1[e][k=h0][n=h1]
    unsigned short w1 = f2bf(W1[t]);
    {   // stage2: row = n (h1), col = k (h0)
        int lane = (((k >> 3) & 3) << 4) | (n & 15);
        W1s2[(e << 16) + ((((n >> 4) * 8 + (k >> 5)) * 64 + lane) << 3) + (k & 7)] = w1;
    }
    {   // stage3: row = k (h0), col = n (h1)
        int lane = (((n >> 3) & 3) << 4) | (k & 15);
        W1s3[(e << 16) + ((((k >> 4) * 8 + (n >> 5)) * 64 + lane) << 3) + (n & 7)] = w1;
    }
    if (k < IN_DIM) {                    // W0[e][d=k][h=n]
        unsigned short w0 = f2bf(W0[e * (IN_DIM * HID) + rem]);
        {   // stage1: row = n (h), col = k (d), K=128 -> KN=4
            int lane = (((k >> 3) & 3) << 4) | (n & 15);
            W0s1[e * (IN_DIM * HID) + ((((n >> 4) * 4 + (k >> 5)) * 64 + lane) << 3) + (k & 7)] = w0;
        }
        {   // stage4: row = k (d), col = n (h), K=256 -> KN=8
            int lane = (((n >> 3) & 3) << 4) | (k & 15);
            W0s4[e * (IN_DIM * HID) + ((((k >> 4) * 8 + (n >> 5)) * 64 + lane) << 3) + (n & 7)] = w0;
        }
    }
}

// ---------------------------------------------------------------------------
// K2) Merged bucket + bin_producer. Binned COO is now PACKED:
//     entry = (col9 << 23) | row  (row < 6.4M < 2^23, col9 = col & 511)
//     -> colsB array eliminated: -8 MB producer write, -8 MB consumer read.
//     Blocks [0, NBP): COO counting-sort by col-bin (col>>9).
//     Blocks [NBP, NBP+BKB): element bucketing + F zeroing.
// ---------------------------------------------------------------------------
__global__ __launch_bounds__(256) void bucket_and_bin(
    const int* __restrict__ Z, int* __restrict__ counts, int* __restrict__ lists,
    float* __restrict__ F,
    const int* __restrict__ rows, const int* __restrict__ cols,
    const float* __restrict__ vals,
    unsigned* __restrict__ packB, float* __restrict__ valsB,
    int* __restrict__ gcur,
    int* __restrict__ ovfR, int* __restrict__ ovfC, float* __restrict__ ovfV,
    int* __restrict__ ocur) {

    __shared__ int   Lr[PCH];
    __shared__ int   Lc[PCH];
    __shared__ float Lv[PCH];
    __shared__ int   hist[CBINS], pref[CBINS], curs[CBINS], gbase[CBINS];

    const int tid = threadIdx.x;

    if (blockIdx.x >= NBP) {
        // ----- bucket part -----
        int* lcnt = hist;          // reuse LDS
        int* lbase = pref;
        const int bb = blockIdx.x - NBP;
        for (int idx = bb * 256 + tid; idx < 3 * N_ATOMS; idx += BKB * 256)
            F[idx] = 0.f;
        const int i = bb * 256 + tid;
        if (tid < N_ELEM) lcnt[tid] = 0;
        __syncthreads();
        int e = -1, pos = 0;
        if (i < N_ATOMS) {
            e = elem_of(Z[i]);
            pos = atomicAdd(&lcnt[e], 1);
        }
        __syncthreads();
        if (tid < N_ELEM)
            lbase[tid] = atomicAdd(&counts[tid], lcnt[tid]);
        __syncthreads();
        if (i < N_ATOMS) lists[e * N_ATOMS + lbase[e] + pos] = i;
        return;
    }

    // ----- producer part -----
    const int base = blockIdx.x * PCH;

    for (int i = tid; i < CBINS; i += 256) hist[i] = 0;
    __syncthreads();

    // phase 1: stash 32 entries (8 x int4 groups, coalesced) + LDS histogram
    i32x4 r[8], c[8];
    fv4   v[8];
    int nvalid[8];
#pragma unroll
    for (int j = 0; j < 8; ++j) {
        const int i0 = base + tid * 4 + 1024 * j;
        int nv = NNZ - i0;
        nvalid[j] = nv > 4 ? 4 : (nv < 0 ? 0 : nv);
        if (nvalid[j] == 4) {
            r[j] = __builtin_nontemporal_load((const i32x4*)(rows + i0));
            c[j] = __builtin_nontemporal_load((const i32x4*)(cols + i0));
            v[j] = __builtin_nontemporal_load((const fv4*)(vals + i0));
        } else {
            for (int e2 = 0; e2 < nvalid[j]; ++e2) {
                r[j][e2] = rows[i0 + e2]; c[j][e2] = cols[i0 + e2];
                v[j][e2] = vals[i0 + e2];
            }
        }
#pragma unroll
        for (int e2 = 0; e2 < 4; ++e2)
            if (e2 < nvalid[j]) atomicAdd(&hist[c[j][e2] >> 9], 1);
    }
    __syncthreads();

    // phase 2: serial prefix (293 tiny) by thread 0
    if (tid == 0) {
        int s = 0;
        for (int b = 0; b < CBINS; ++b) { pref[b] = s; s += hist[b]; }
    }
    __syncthreads();
    // phase 2.5: reserve global ranges; init cursors
    for (int b = tid; b < CBINS; b += 256) {
        gbase[b] = atomicAdd(&gcur[b], hist[b]);
        curs[b] = pref[b];
    }
    __syncthreads();

    // phase 3: scatter into LDS (counting-sort order)
#pragma unroll
    for (int j = 0; j < 8; ++j)
#pragma unroll
        for (int e2 = 0; e2 < 4; ++e2)
            if (e2 < nvalid[j]) {
                int b = c[j][e2] >> 9;
                int p = atomicAdd(&curs[b], 1);
                Lr[p] = r[j][e2]; Lc[p] = c[j][e2]; Lv[p] = v[j][e2];
            }
    __syncthreads();

    // phase 4: linear LDS -> global, packed (runs per bin = coalesced)
    const int total = (base + PCH <= NNZ) ? PCH : (NNZ - base);
#pragma unroll
    for (int j = 0; j < 32; ++j) {
        const int p = tid + 256 * j;
        if (p >= total) break;
        const int col = Lc[p];
        const int b = col >> 9;
        const int g = gbase[b] + (p - pref[b]);
        if (g < BCAP) {
            packB[b * BCAP + g] = ((unsigned)(col & 511) << 23) | (unsigned)Lr[p];
            valsB[b * BCAP + g] = Lv[p];
        } else {
            int od = atomicAdd(ocur, 1);
            if (od < OCAP) { ovfR[od] = Lr[p]; ovfC[od] = col; ovfV[od] = Lv[p]; }
        }
    }
}

// ---------------------------------------------------------------------------
// K3) FULLY-FUSED MLP fwd+bwd — R17 post-mortem: occupancy worth ~8us/step,
//     stride-36 is the conflict-free stride (300k vs 1.25M at 40, 4.5M at
//     34). This round combines the wins: M=32 + stride 36 + 4 blocks/CU
//     (37.4 KB LDS -> 149.5 KB/CU, 16 waves). Chunk = 32*36 = 1152 shorts.
//     Swizzled coalesced B loads + ring prefetch + barrier-free K-loops.
// ---------------------------------------------------------------------------
#define TILES_PER_E 512   // 32-row tiles
#define CH 1152           // chunk stride in shorts (32*36)
__global__ __launch_bounds__(256, 4) void fused_mlp(
    const float* __restrict__ fp,
    const unsigned short* __restrict__ W0s1,
    const unsigned short* __restrict__ W1s2,
    const unsigned short* __restrict__ W1s3,
    const unsigned short* __restrict__ W0s4,
    const float* __restrict__ b0, const float* __restrict__ b1,
    const float* __restrict__ W2, const float* __restrict__ b2,
    float* __restrict__ o_atom,
    unsigned short* __restrict__ Gb,
    const int* __restrict__ counts, const int* __restrict__ lists) {

    const int bid = blockIdx.x;
    const int xcd = bid & 7;
    const int e = xcd & 3;                       // element pinned to XCD pair
    const int tile = (bid >> 3) * 2 + (xcd >> 2);
    const int cnt = counts[e];
    const int m0 = tile * 32;
    if (m0 >= cnt) return;
    const int* list = lists + e * N_ATOMS;

    __shared__ short tH[8 * CH];           // 18432 B
    __shared__ short tD[8 * CH];           // 18432 B
    __shared__ float red[4][32];           // 512 B   (total 37376 B)

    const int tid = threadIdx.x;
    const int lane = tid & 63;
    const int wv = tid >> 6;       // 0..3, n-range wv*64
    const int lr = lane & 15;
    const int lq = lane >> 4;

    const unsigned short* B1 = W0s1 + (size_t)e * HID * IN_DIM;
    const unsigned short* B2 = W1s2 + (size_t)e * HID * HID;
    const unsigned short* B3 = W1s3 + (size_t)e * HID * HID;
    const unsigned short* B4 = W0s4 + (size_t)e * IN_DIM * HID;

    // A-row pointers for the 2 m-tiles (rows mt*16 + lr)
    const float* arow[2];
    bool aok[2];
#pragma unroll
    for (int mt = 0; mt < 2; ++mt) {
        int m = m0 + mt * 16 + lr;
        aok[mt] = (m < cnt);
        arow[mt] = aok[mt] ? (fp + (size_t)list[m] * IN_DIM) : fp;
    }

    f32x4 acc[2][4];
#define ZERO_ACC()                                                        \
    _Pragma("unroll") for (int mt = 0; mt < 2; ++mt)                      \
        _Pragma("unroll") for (int nt = 0; nt < 4; ++nt)                  \
            _Pragma("unroll") for (int j = 0; j < 4; ++j) acc[mt][nt][j] = 0.f;

    // =============== Stage 1: z0 = fp @ W0^T   (K=128, KN=4, ring-2) ======
    ZERO_ACC();
    {
        float4 a0[2][2], a1[2][2];
        bf16x8 bb[2][4];
#pragma unroll
        for (int mt = 0; mt < 2; ++mt) if (aok[mt]) {
            a0[0][mt] = *(const float4*)(arow[mt] + lq * 8);
            a1[0][mt] = *(const float4*)(arow[mt] + lq * 8 + 4);
        }
#pragma unroll
        for (int nt = 0; nt < 4; ++nt)
            bb[0][nt] = *(const bf16x8*)(B1 +
                ((size_t)(((wv * 4 + nt) * 4 + 0) * 64 + lane) << 3));
#pragma unroll
        for (int ki = 0; ki < 4; ++ki) {
            const int cur = ki & 1, nx = cur ^ 1;
            if (ki < 3) {
                const int k0n = (ki + 1) * 32;
#pragma unroll
                for (int mt = 0; mt < 2; ++mt) if (aok[mt]) {
                    a0[nx][mt] = *(const float4*)(arow[mt] + k0n + lq * 8);
                    a1[nx][mt] = *(const float4*)(arow[mt] + k0n + lq * 8 + 4);
                }
#pragma unroll
                for (int nt = 0; nt < 4; ++nt)
                    bb[nx][nt] = *(const bf16x8*)(B1 +
                        ((size_t)(((wv * 4 + nt) * 4 + ki + 1) * 64 + lane) << 3));
            }
            bf16x8 af[2];
#pragma unroll
            for (int mt = 0; mt < 2; ++mt) {
                bf16x8 vv;
#pragma unroll
                for (int j = 0; j < 8; ++j) vv[j] = 0;
                if (aok[mt]) {
                    vv[0] = (short)f2bf(a0[cur][mt].x); vv[1] = (short)f2bf(a0[cur][mt].y);
                    vv[2] = (short)f2bf(a0[cur][mt].z); vv[3] = (short)f2bf(a0[cur][mt].w);
                    vv[4] = (short)f2bf(a1[cur][mt].x); vv[5] = (short)f2bf(a1[cur][mt].y);
                    vv[6] = (short)f2bf(a1[cur][mt].z); vv[7] = (short)f2bf(a1[cur][mt].w);
                }
                af[mt] = vv;
            }
#pragma unroll
            for (int mt = 0; mt < 2; ++mt)
#pragma unroll
                for (int nt = 0; nt < 4; ++nt)
                    acc[mt][nt] = __builtin_amdgcn_mfma_f32_16x16x32_bf16(
                        af[mt], bb[cur][nt], acc[mt][nt], 0, 0, 0);
        }
    }

    // S2 B-ring preload (hoisted: flies during epilogue-1 VALU + barrier)
    bf16x8 b2r[3][4];
#pragma unroll
    for (int p = 0; p < 3; ++p)
#pragma unroll
        for (int nt = 0; nt < 4; ++nt)
            b2r[p][nt] = *(const bf16x8*)(B2 +
                ((size_t)(((wv * 4 + nt) * 8 + p) * 64 + lane) << 3));

    // epilogue 1: h0 -> tH
    {
        float bv[4];
#pragma unroll
        for (int nt = 0; nt < 4; ++nt)
            bv[nt] = b0[e * HID + wv * 64 + nt * 16 + lr];
#pragma unroll
        for (int mt = 0; mt < 2; ++mt)
#pragma unroll
            for (int rr = 0; rr < 4; ++rr) {
                const int row = mt * 16 + lq * 4 + rr;
#pragma unroll
                for (int nt = 0; nt < 4; ++nt) {
                    const int n = wv * 64 + nt * 16 + lr;
                    float t = tanh_fast(acc[mt][nt][rr] + bv[nt]);
                    tH[(n >> 5) * CH + row * 36 + (n & 31)] = (short)f2bf(t);
                }
            }
    }
    __syncthreads();

    // =============== Stage 2: z1 = h0 @ W1^T   (K=256, ring-3) =============
    ZERO_ACC();
#pragma unroll
    for (int ki = 0; ki < 8; ++ki) {
        bf16x8 af[2];
#pragma unroll
        for (int mt = 0; mt < 2; ++mt)
            af[mt] = *(const bf16x8*)&tH[ki * CH + (mt * 16 + lr) * 36 + lq * 8];
#pragma unroll
        for (int mt = 0; mt < 2; ++mt)
#pragma unroll
            for (int nt = 0; nt < 4; ++nt)
                acc[mt][nt] = __builtin_amdgcn_mfma_f32_16x16x32_bf16(
                    af[mt], b2r[ki % 3][nt], acc[mt][nt], 0, 0, 0);
        if (ki < 5) {
#pragma unroll
            for (int nt = 0; nt < 4; ++nt)
                b2r[ki % 3][nt] = *(const bf16x8*)(B2 +
                    ((size_t)(((wv * 4 + nt) * 8 + ki + 3) * 64 + lane) << 3));
        }
    }

    // S3 B-ring preload (hoisted above epilogue-2 + barrier)
    bf16x8 b3r[3][4];
#pragma unroll
    for (int p = 0; p < 3; ++p)
#pragma unroll
        for (int nt = 0; nt < 4; ++nt)
            b3r[p][nt] = *(const bf16x8*)(B3 +
                ((size_t)(((wv * 4 + nt) * 8 + p) * 64 + lane) << 3));

    // epilogue 2: dz1 -> tD; o partials -> red
    {
        float bv[4], w2v[4];
#pragma unroll
        for (int nt = 0; nt < 4; ++nt) {
            bv[nt]  = b1[e * HID + wv * 64 + nt * 16 + lr];
            w2v[nt] = W2[e * HID + wv * 64 + nt * 16 + lr];
        }
#pragma unroll
        for (int mt = 0; mt < 2; ++mt)
#pragma unroll
            for (int rr = 0; rr < 4; ++rr) {
                const int row = mt * 16 + lq * 4 + rr;
                float osum = 0.f;
#pragma unroll
                for (int nt = 0; nt < 4; ++nt) {
                    const int n = wv * 64 + nt * 16 + lr;
                    float t = tanh_fast(acc[mt][nt][rr] + bv[nt]);
                    osum += t * w2v[nt];
                    tD[(n >> 5) * CH + row * 36 + (n & 31)] =
                        (short)f2bf(w2v[nt] * (1.f - t * t));
                }
                osum += __shfl_xor(osum, 1, 64);
                osum += __shfl_xor(osum, 2, 64);
                osum += __shfl_xor(osum, 4, 64);
                osum += __shfl_xor(osum, 8, 64);
                if (lr == 0) red[wv][row] = osum;
            }
    }
    __syncthreads();
    if (tid < 32) {
        int m = m0 + tid;
        if (m < cnt)
            o_atom[list[m]] = red[0][tid] + red[1][tid] + red[2][tid] +
                              red[3][tid] + b2[e];
    }

    // =============== Stage 3: dh0 = dz1 @ W1   (K=256, ring-3) =============
    ZERO_ACC();
#pragma unroll
    for (int ki = 0; ki < 8; ++ki) {
        bf16x8 af[2];
#pragma unroll
        for (int mt = 0; mt < 2; ++mt)
            af[mt] = *(const bf16x8*)&tD[ki * CH + (mt * 16 + lr) * 36 + lq * 8];
#pragma unroll
        for (int mt = 0; mt < 2; ++mt)
#pragma unroll
            for (int nt = 0; nt < 4; ++nt)
                acc[mt][nt] = __builtin_amdgcn_mfma_f32_16x16x32_bf16(
                    af[mt], b3r[ki % 3][nt], acc[mt][nt], 0, 0, 0);
        if (ki < 5) {
#pragma unroll
            for (int nt = 0; nt < 4; ++nt)
                b3r[ki % 3][nt] = *(const bf16x8*)(B3 +
                    ((size_t)(((wv * 4 + nt) * 8 + ki + 3) * 64 + lane) << 3));
        }
    }

    // S4 B-ring preload (hoisted above epilogue-3 + barrier)
    bf16x8 b4r[3][2];
#pragma unroll
    for (int p = 0; p < 3; ++p)
#pragma unroll
        for (int nt = 0; nt < 2; ++nt)
            b4r[p][nt] = *(const bf16x8*)(B4 +
                ((size_t)(((wv * 2 + nt) * 8 + p) * 64 + lane) << 3));

    // epilogue 3: dz0 = dh0*(1-h0^2) -> tH in-place (same thread owns slot)
#pragma unroll
    for (int mt = 0; mt < 2; ++mt)
#pragma unroll
        for (int rr = 0; rr < 4; ++rr) {
            const int row = mt * 16 + lq * 4 + rr;
#pragma unroll
            for (int nt = 0; nt < 4; ++nt) {
                const int n = wv * 64 + nt * 16 + lr;
                const int a = (n >> 5) * CH + row * 36 + (n & 31);
                float h = bf2f((unsigned short)tH[a]);
                tH[a] = (short)f2bf(acc[mt][nt][rr] * (1.f - h * h));
            }
        }
    __syncthreads();

    // =============== Stage 4: g = dz0 @ W0   (K=256, NT=2, ring-3) =========
    {
        f32x4 a4[2][2];
#pragma unroll
        for (int mt = 0; mt < 2; ++mt)
#pragma unroll
            for (int nt = 0; nt < 2; ++nt)
#pragma unroll
                for (int j = 0; j < 4; ++j) a4[mt][nt][j] = 0.f;
#pragma unroll
        for (int ki = 0; ki < 8; ++ki) {
            bf16x8 af[2];
#pragma unroll
            for (int mt = 0; mt < 2; ++mt)
                af[mt] = *(const bf16x8*)&tH[ki * CH + (mt * 16 + lr) * 36 + lq * 8];
#pragma unroll
            for (int mt = 0; mt < 2; ++mt)
#pragma unroll
                for (int nt = 0; nt < 2; ++nt)
                    a4[mt][nt] = __builtin_amdgcn_mfma_f32_16x16x32_bf16(
                        af[mt], b4r[ki % 3][nt], a4[mt][nt], 0, 0, 0);
            if (ki < 5) {
#pragma unroll
                for (int nt = 0; nt < 2; ++nt)
                    b4r[ki % 3][nt] = *(const bf16x8*)(B4 +
                        ((size_t)(((wv * 2 + nt) * 8 + ki + 3) * 64 + lane) << 3));
            }
        }
        // epilogue 4: g -> tD chunk-major, then coalesced bf16x8 scatter
#pragma unroll
        for (int mt = 0; mt < 2; ++mt)
#pragma unroll
            for (int rr = 0; rr < 4; ++rr) {
                const int row = mt * 16 + lq * 4 + rr;
#pragma unroll
                for (int nt = 0; nt < 2; ++nt) {
                    const int n = wv * 32 + nt * 16 + lr;
                    tD[(n >> 5) * CH + row * 36 + (n & 31)] =
                        (short)f2bf(a4[mt][nt][rr]);
                }
            }
    }
    __syncthreads();
#pragma unroll
    for (int t = 0; t < 2; ++t) {
        const int c = tid + 256 * t;         // 0..511
        const int row = c >> 4;              // 0..31
        const int pos = (c & 15) * 8;        // 0..120
        const int m = m0 + row;
        if (m < cnt) {
            bf16x8 v = *(const bf16x8*)&tD[(pos >> 5) * CH + row * 36 + (pos & 31)];
            *(bf16x8*)(Gb + (size_t)list[m] * IN_DIM + pos) = v;
        }
    }
#undef ZERO_ACC
}

// ---------------------------------------------------------------------------
// K4) Forces consumer — 1024 threads, exclusive col-window in LDS, zero
//     global atomics. Binned entries packed (col9<<23)|row.
//     Blocks < N_IMG also reduce their image's energy.
// ---------------------------------------------------------------------------
__global__ __launch_bounds__(1024) void forces_consumer(
    const unsigned* __restrict__ packB, const float* __restrict__ valsB,
    const int* __restrict__ gcur,
    const unsigned short* __restrict__ g, float* __restrict__ F,
    const float* __restrict__ o_atom, const int* __restrict__ img,
    float* __restrict__ energy,
    const int* __restrict__ ovfR, const int* __restrict__ ovfC,
    const float* __restrict__ ovfV, const int* __restrict__ ocur) {

    const int blk = blockIdx.x;
    __shared__ float win[CW];

    if (blk < CBINS) {
        for (int i = threadIdx.x; i < CW; i += 1024) win[i] = 0.f;
        __syncthreads();
        const int w0 = blk << 9;
        int cnt = gcur[blk]; if (cnt > BCAP) cnt = BCAP;
        const size_t o = (size_t)blk * BCAP;
        for (int idx0 = (int)threadIdx.x * 4; idx0 < cnt; idx0 += 4096) {
            if (idx0 + 4 <= cnt) {
                i32x4 p = *(const i32x4*)((const int*)packB + o + idx0);
                fv4   v = *(const fv4*)(valsB + o + idx0);
                unsigned p0 = (unsigned)p[0], p1 = (unsigned)p[1];
                unsigned p2 = (unsigned)p[2], p3 = (unsigned)p[3];
                float g0 = bf2f(g[p0 & 0x7FFFFFu]), g1 = bf2f(g[p1 & 0x7FFFFFu]);
                float g2 = bf2f(g[p2 & 0x7FFFFFu]), g3 = bf2f(g[p3 & 0x7FFFFFu]);
                atomicAdd(&win[p0 >> 23], -v[0] * g0);
                atomicAdd(&win[p1 >> 23], -v[1] * g1);
                atomicAdd(&win[p2 >> 23], -v[2] * g2);
                atomicAdd(&win[p3 >> 23], -v[3] * g3);
            } else {
                for (int e2 = idx0; e2 < cnt; ++e2) {
                    unsigned p0 = packB[o + e2];
                    atomicAdd(&win[p0 >> 23],
                              -valsB[o + e2] * bf2f(g[p0 & 0x7FFFFFu]));
                }
            }
        }
        // fold overflow entries belonging to this window (expected none)
        int ocnt = ocur[0]; if (ocnt > OCAP) ocnt = OCAP;
        for (int k2 = threadIdx.x; k2 < ocnt; k2 += 1024) {
            int c = ovfC[k2];
            if (c >= w0 && c < w0 + CW)
                atomicAdd(&win[c - w0], -ovfV[k2] * bf2f(g[ovfR[k2]]));
        }
        __syncthreads();
        for (int i = threadIdx.x; i < CW; i += 1024) {
            int c = w0 + i;
            if (c < 3 * N_ATOMS) F[c] = win[i];
        }
    }

    // energy fold
    if (blk < N_IMG) {
        const int bb = blk;
        int lo, hi;
        {
            int l = 0, r = N_ATOMS;
            while (l < r) { int m = (l + r) >> 1; if (img[m] < bb) l = m + 1; else r = m; }
            lo = l;
        }
        {
            int l = lo, r = N_ATOMS;
            while (l < r) { int m = (l + r) >> 1; if (img[m] < bb + 1) l = m + 1; else r = m; }
            hi = l;
        }
        float s = 0.f;
        for (int i2 = lo + (int)threadIdx.x; i2 < hi; i2 += 1024) s += o_atom[i2];
#pragma unroll
        for (int off = 32; off > 0; off >>= 1) s += __shfl_down(s, off, 64);
        __shared__ float red[16];
        if ((threadIdx.x & 63) == 0) red[threadIdx.x >> 6] = s;
        __syncthreads();
        if (threadIdx.x == 0) {
            float t = 0.f;
#pragma unroll
            for (int w = 0; w < 16; ++w) t += red[w];
            energy[bb] = t;
        }
    }
}

// ---------------------------------------------------------------------------
extern "C" void kernel_launch(void* const* d_in, const int* in_sizes, int n_in,
                              void* d_out, int out_size, void* d_ws, size_t ws_size,
                              hipStream_t stream) {
    const float* fp    = (const float*)d_in[0];
    const int*   Z     = (const int*)d_in[1];
    const int*   img   = (const int*)d_in[2];
    const int*   frows = (const int*)d_in[3];
    const int*   fcols = (const int*)d_in[4];
    const float* fvals = (const float*)d_in[5];
    const float* W0    = (const float*)d_in[6];
    const float* b0    = (const float*)d_in[7];
    const float* W1    = (const float*)d_in[8];
    const float* b1    = (const float*)d_in[9];
    const float* W2    = (const float*)d_in[10];
    const float* b2    = (const float*)d_in[11];

    float* out    = (float*)d_out;
    float* energy = out;             // [N_IMG]
    float* F      = out + N_IMG;     // [3*N_ATOMS]

    char* ws = (char*)d_ws;
    int*   counts = (int*)ws;                                   // 16 B
    int*   lists  = (int*)(ws + 1024);                          // 800 KB
    char*  base   = ws + (1 << 20);
    unsigned short* Gb   = (unsigned short*)(base);              // 12.8 MB (atom order)
    float* o_atom        = (float*)(base + 13000000);            // 200 KB
    unsigned short* W0s1 = (unsigned short*)(base + 14000000);   // 256 KB
    unsigned short* W0s4 = W0s1 + N_ELEM * IN_DIM * HID;
    unsigned short* W1s2 = W0s4 + N_ELEM * IN_DIM * HID;
    unsigned short* W1s3 = W1s2 + N_ELEM * HID * HID;
    int*   gcur  = (int*)(base + 18000000);                      // 293 ints
    int*   ocur  = (int*)(base + 18002048);
    unsigned* packB = (unsigned*)(base + 19000000);              // 9.6 MB
    float* valsB = (float*)(base + 29000000);                    // 9.6 MB
    int*   ovfR  = (int*)(base + 49000000);
    int*   ovfC  = (int*)(base + 49050000);
    float* ovfV  = (float*)(base + 49100000);

    // 4 dispatches: prep(+cursors) -> bucket&bin -> fused -> consumer(+energy)
    prep_weights<<<(N_ELEM * HID * HID + 255) / 256, 256, 0, stream>>>(
        W0, W1, W0s1, W1s2, W1s3, W0s4, counts, gcur, ocur);

    bucket_and_bin<<<NBP + BKB, 256, 0, stream>>>(
        Z, counts, lists, F, frows, fcols, fvals,
        packB, valsB, gcur, ovfR, ovfC, ovfV, ocur);

    fused_mlp<<<8 * (TILES_PER_E / 2), 256, 0, stream>>>(
        fp, W0s1, W1s2, W1s3, W0s4, b0, b1, W2, b2, o_atom, Gb, counts, lists);

    forces_consumer<<<N_IMG, 1024, 0, stream>>>(
        packB, valsB, gcur, Gb, F, o_atom, img, energy,
        ovfR, ovfC, ovfV, ocur);
}

// Round 19
// 214.727 us; speedup vs baseline: 1.0633x; 1.0633x over previous
//
#include <hip/hip_runtime.h>
#include <math.h>

#define N_ATOMS 50000
#define IN_DIM 128
#define HID 256
#define N_ELEM 4
#define N_IMG 500
#define NNZ 2000000

// forces col-binning (R14: zero global atomics, consumer owns col-windows)
#define CBINS 293        // col >> 9 over 150,016 cols
#define CW 512           // cols per bin (2 KB LDS window)
#define BCAP 8192        // expect 6826 +- 83 (16 sigma headroom)
#define OCAP 4096        // overflow list capacity (expected use: 0)
#define PCH 8192         // producer chunk (entries per block)
#define NBP ((NNZ + PCH - 1) / PCH)   // 245 producer blocks
#define BKB ((N_ATOMS + 255) / 256)   // 196 bucket blocks

typedef __attribute__((ext_vector_type(8))) short bf16x8;   // 8 bf16 = 4 VGPRs
typedef __attribute__((ext_vector_type(4))) float f32x4;    // MFMA C/D frag
typedef __attribute__((ext_vector_type(4))) int   i32x4;    // native vec loads
typedef __attribute__((ext_vector_type(4))) float fv4;      // native vec loads

__device__ __forceinline__ int elem_of(int z) {
    return (z == 1) ? 0 : (z == 6) ? 1 : (z == 8) ? 2 : 3;
}

__device__ __forceinline__ unsigned short f2bf(float f) {   // RNE
    unsigned u = __float_as_uint(f);
    u += 0x7fffu + ((u >> 16) & 1u);
    return (unsigned short)(u >> 16);
}
__device__ __forceinline__ float bf2f(unsigned short u) {
    return __uint_as_float(((unsigned)u) << 16);
}
__device__ __forceinline__ float tanh_fast(float x) {
    float e = __expf(2.f * x);
    return (e - 1.f) / (e + 1.f);
}

// ---------------------------------------------------------------------------
// K1) Weight prep — pre-swizzle into wave-frag order (R9: worth 44us).
//     Block 0 also zeroes counts + binning cursors (consumed next dispatch).
// ---------------------------------------------------------------------------
__global__ __launch_bounds__(256) void prep_weights(
    const float* __restrict__ W0, const float* __restrict__ W1,
    unsigned short* __restrict__ W0s1,   // stage1: Bt[h][d], K=128, KN=4
    unsigned short* __restrict__ W1s2,   // stage2: Bt[h1][h0], K=256, KN=8
    unsigned short* __restrict__ W1s3,   // stage3: Bt[h0][h1], K=256, KN=8
    unsigned short* __restrict__ W0s4,   // stage4: Bt[d][h], K=256, KN=8
    int* __restrict__ counts, int* __restrict__ gcur, int* __restrict__ ocur) {
    if (blockIdx.x == 0) {
        if (threadIdx.x < N_ELEM) counts[threadIdx.x] = 0;
        for (int i = threadIdx.x; i < CBINS; i += 256) gcur[i] = 0;
        if (threadIdx.x == 0) ocur[0] = 0;
    }
    int t = blockIdx.x * 256 + threadIdx.x;
    if (t >= N_ELEM * HID * HID) return;
    int e = t >> 16;
    int rem = t & 65535;
    int k = rem >> 8, n = rem & 255;     // W1[e][k=h0][n=h1]
    unsigned short w1 = f2bf(W1[t]);
    {   // stage2: row = n (h1), col = k (h0)
        int lane = (((k >> 3) & 3) << 4) | (n & 15);
        W1s2[(e << 16) + ((((n >> 4) * 8 + (k >> 5)) * 64 + lane) << 3) + (k & 7)] = w1;
    }
    {   // stage3: row = k (h0), col = n (h1)
        int lane = (((n >> 3) & 3) << 4) | (k & 15);
        W1s3[(e << 16) + ((((k >> 4) * 8 + (n >> 5)) * 64 + lane) << 3) + (n & 7)] = w1;
    }
    if (k < IN_DIM) {                    // W0[e][d=k][h=n]
        unsigned short w0 = f2bf(W0[e * (IN_DIM * HID) + rem]);
        {   // stage1: row = n (h), col = k (d), K=128 -> KN=4
            int lane = (((k >> 3) & 3) << 4) | (n & 15);
            W0s1[e * (IN_DIM * HID) + ((((n >> 4) * 4 + (k >> 5)) * 64 + lane) << 3) + (k & 7)] = w0;
        }
        {   // stage4: row = k (d), col = n (h), K=256 -> KN=8
            int lane = (((n >> 3) & 3) << 4) | (k & 15);
            W0s4[e * (IN_DIM * HID) + ((((k >> 4) * 8 + (n >> 5)) * 64 + lane) << 3) + (n & 7)] = w0;
        }
    }
}

// ---------------------------------------------------------------------------
// K2) Merged bucket + bin_producer. Binned COO PACKED:
//     entry = (col9 << 23) | row  (row < 6.4M < 2^23, col9 = col & 511).
//     Blocks [0, NBP): COO counting-sort by col-bin (col>>9).
//     Blocks [NBP, NBP+BKB): element bucketing + F zeroing.
// ---------------------------------------------------------------------------
__global__ __launch_bounds__(256) void bucket_and_bin(
    const int* __restrict__ Z, int* __restrict__ counts, int* __restrict__ lists,
    float* __restrict__ F,
    const int* __restrict__ rows, const int* __restrict__ cols,
    const float* __restrict__ vals,
    unsigned* __restrict__ packB, float* __restrict__ valsB,
    int* __restrict__ gcur,
    int* __restrict__ ovfR, int* __restrict__ ovfC, float* __restrict__ ovfV,
    int* __restrict__ ocur) {

    __shared__ int   Lr[PCH];
    __shared__ int   Lc[PCH];
    __shared__ float Lv[PCH];
    __shared__ int   hist[CBINS], pref[CBINS], curs[CBINS], gbase[CBINS];

    const int tid = threadIdx.x;

    if (blockIdx.x >= NBP) {
        // ----- bucket part -----
        int* lcnt = hist;          // reuse LDS
        int* lbase = pref;
        const int bb = blockIdx.x - NBP;
        for (int idx = bb * 256 + tid; idx < 3 * N_ATOMS; idx += BKB * 256)
            F[idx] = 0.f;
        const int i = bb * 256 + tid;
        if (tid < N_ELEM) lcnt[tid] = 0;
        __syncthreads();
        int e = -1, pos = 0;
        if (i < N_ATOMS) {
            e = elem_of(Z[i]);
            pos = atomicAdd(&lcnt[e], 1);
        }
        __syncthreads();
        if (tid < N_ELEM)
            lbase[tid] = atomicAdd(&counts[tid], lcnt[tid]);
        __syncthreads();
        if (i < N_ATOMS) lists[e * N_ATOMS + lbase[e] + pos] = i;
        return;
    }

    // ----- producer part -----
    const int base = blockIdx.x * PCH;

    for (int i = tid; i < CBINS; i += 256) hist[i] = 0;
    __syncthreads();

    // phase 1: stash 32 entries (8 x int4 groups, coalesced) + LDS histogram
    i32x4 r[8], c[8];
    fv4   v[8];
    int nvalid[8];
#pragma unroll
    for (int j = 0; j < 8; ++j) {
        const int i0 = base + tid * 4 + 1024 * j;
        int nv = NNZ - i0;
        nvalid[j] = nv > 4 ? 4 : (nv < 0 ? 0 : nv);
        if (nvalid[j] == 4) {
            r[j] = __builtin_nontemporal_load((const i32x4*)(rows + i0));
            c[j] = __builtin_nontemporal_load((const i32x4*)(cols + i0));
            v[j] = __builtin_nontemporal_load((const fv4*)(vals + i0));
        } else {
            for (int e2 = 0; e2 < nvalid[j]; ++e2) {
                r[j][e2] = rows[i0 + e2]; c[j][e2] = cols[i0 + e2];
                v[j][e2] = vals[i0 + e2];
            }
        }
#pragma unroll
        for (int e2 = 0; e2 < 4; ++e2)
            if (e2 < nvalid[j]) atomicAdd(&hist[c[j][e2] >> 9], 1);
    }
    __syncthreads();

    // phase 2: serial prefix (293 tiny) by thread 0
    if (tid == 0) {
        int s = 0;
        for (int b = 0; b < CBINS; ++b) { pref[b] = s; s += hist[b]; }
    }
    __syncthreads();
    // phase 2.5: reserve global ranges; init cursors
    for (int b = tid; b < CBINS; b += 256) {
        gbase[b] = atomicAdd(&gcur[b], hist[b]);
        curs[b] = pref[b];
    }
    __syncthreads();

    // phase 3: scatter into LDS (counting-sort order)
#pragma unroll
    for (int j = 0; j < 8; ++j)
#pragma unroll
        for (int e2 = 0; e2 < 4; ++e2)
            if (e2 < nvalid[j]) {
                int b = c[j][e2] >> 9;
                int p = atomicAdd(&curs[b], 1);
                Lr[p] = r[j][e2]; Lc[p] = c[j][e2]; Lv[p] = v[j][e2];
            }
    __syncthreads();

    // phase 4: linear LDS -> global, packed (runs per bin = coalesced)
    const int total = (base + PCH <= NNZ) ? PCH : (NNZ - base);
#pragma unroll
    for (int j = 0; j < 32; ++j) {
        const int p = tid + 256 * j;
        if (p >= total) break;
        const int col = Lc[p];
        const int b = col >> 9;
        const int g = gbase[b] + (p - pref[b]);
        if (g < BCAP) {
            packB[b * BCAP + g] = ((unsigned)(col & 511) << 23) | (unsigned)Lr[p];
            valsB[b * BCAP + g] = Lv[p];
        } else {
            int od = atomicAdd(ocur, 1);
            if (od < OCAP) { ovfR[od] = Lr[p]; ovfC[od] = col; ovfV[od] = Lv[p]; }
        }
    }
}

// ---------------------------------------------------------------------------
// K3) FULLY-FUSED MLP fwd+bwd — R18 post-mortem: the matrix of
//     {stride, blocks/CU} configs measured: s40/3blk = 60.3us (R17, total
//     218.6) beats s36/2blk = 68 (R16) and s36/4blk = 72 + doubled FETCH
//     (R18 — 128 co-resident tiles/XCD thrash L1/L2 on fp/weight streams).
//     REVERTED to R17's exact measured-best: M=32, stride 40, 3 blocks/CU.
//     Swizzled coalesced B loads + ring prefetch + barrier-free K-loops.
// ---------------------------------------------------------------------------
#define TILES_PER_E 512   // 32-row tiles
#define CH 1280           // chunk stride in shorts (32*40)
__global__ __launch_bounds__(256, 3) void fused_mlp(
    const float* __restrict__ fp,
    const unsigned short* __restrict__ W0s1,
    const unsigned short* __restrict__ W1s2,
    const unsigned short* __restrict__ W1s3,
    const unsigned short* __restrict__ W0s4,
    const float* __restrict__ b0, const float* __restrict__ b1,
    const float* __restrict__ W2, const float* __restrict__ b2,
    float* __restrict__ o_atom,
    unsigned short* __restrict__ Gb,
    const int* __restrict__ counts, const int* __restrict__ lists) {

    const int bid = blockIdx.x;
    const int xcd = bid & 7;
    const int e = xcd & 3;                       // element pinned to XCD pair
    const int tile = (bid >> 3) * 2 + (xcd >> 2);
    const int cnt = counts[e];
    const int m0 = tile * 32;
    if (m0 >= cnt) return;
    const int* list = lists + e * N_ATOMS;

    __shared__ short tH[8 * CH];           // 20480 B
    __shared__ short tD[8 * CH];           // 20480 B
    __shared__ float red[4][32];           // 512 B   (total 41.5 KB)

    const int tid = threadIdx.x;
    const int lane = tid & 63;
    const int wv = tid >> 6;       // 0..3, n-range wv*64
    const int lr = lane & 15;
    const int lq = lane >> 4;

    const unsigned short* B1 = W0s1 + (size_t)e * HID * IN_DIM;
    const unsigned short* B2 = W1s2 + (size_t)e * HID * HID;
    const unsigned short* B3 = W1s3 + (size_t)e * HID * HID;
    const unsigned short* B4 = W0s4 + (size_t)e * IN_DIM * HID;

    // A-row pointers for the 2 m-tiles (rows mt*16 + lr)
    const float* arow[2];
    bool aok[2];
#pragma unroll
    for (int mt = 0; mt < 2; ++mt) {
        int m = m0 + mt * 16 + lr;
        aok[mt] = (m < cnt);
        arow[mt] = aok[mt] ? (fp + (size_t)list[m] * IN_DIM) : fp;
    }

    f32x4 acc[2][4];
#define ZERO_ACC()                                                        \
    _Pragma("unroll") for (int mt = 0; mt < 2; ++mt)                      \
        _Pragma("unroll") for (int nt = 0; nt < 4; ++nt)                  \
            _Pragma("unroll") for (int j = 0; j < 4; ++j) acc[mt][nt][j] = 0.f;

    // =============== Stage 1: z0 = fp @ W0^T   (K=128, KN=4, ring-2) ======
    ZERO_ACC();
    {
        float4 a0[2][2], a1[2][2];
        bf16x8 bb[2][4];
#pragma unroll
        for (int mt = 0; mt < 2; ++mt) if (aok[mt]) {
            a0[0][mt] = *(const float4*)(arow[mt] + lq * 8);
            a1[0][mt] = *(const float4*)(arow[mt] + lq * 8 + 4);
        }
#pragma unroll
        for (int nt = 0; nt < 4; ++nt)
            bb[0][nt] = *(const bf16x8*)(B1 +
                ((size_t)(((wv * 4 + nt) * 4 + 0) * 64 + lane) << 3));
#pragma unroll
        for (int ki = 0; ki < 4; ++ki) {
            const int cur = ki & 1, nx = cur ^ 1;
            if (ki < 3) {
                const int k0n = (ki + 1) * 32;
#pragma unroll
                for (int mt = 0; mt < 2; ++mt) if (aok[mt]) {
                    a0[nx][mt] = *(const float4*)(arow[mt] + k0n + lq * 8);
                    a1[nx][mt] = *(const float4*)(arow[mt] + k0n + lq * 8 + 4);
                }
#pragma unroll
                for (int nt = 0; nt < 4; ++nt)
                    bb[nx][nt] = *(const bf16x8*)(B1 +
                        ((size_t)(((wv * 4 + nt) * 4 + ki + 1) * 64 + lane) << 3));
            }
            bf16x8 af[2];
#pragma unroll
            for (int mt = 0; mt < 2; ++mt) {
                bf16x8 vv;
#pragma unroll
                for (int j = 0; j < 8; ++j) vv[j] = 0;
                if (aok[mt]) {
                    vv[0] = (short)f2bf(a0[cur][mt].x); vv[1] = (short)f2bf(a0[cur][mt].y);
                    vv[2] = (short)f2bf(a0[cur][mt].z); vv[3] = (short)f2bf(a0[cur][mt].w);
                    vv[4] = (short)f2bf(a1[cur][mt].x); vv[5] = (short)f2bf(a1[cur][mt].y);
                    vv[6] = (short)f2bf(a1[cur][mt].z); vv[7] = (short)f2bf(a1[cur][mt].w);
                }
                af[mt] = vv;
            }
#pragma unroll
            for (int mt = 0; mt < 2; ++mt)
#pragma unroll
                for (int nt = 0; nt < 4; ++nt)
                    acc[mt][nt] = __builtin_amdgcn_mfma_f32_16x16x32_bf16(
                        af[mt], bb[cur][nt], acc[mt][nt], 0, 0, 0);
        }
    }

    // S2 B-ring preload (hoisted: flies during epilogue-1 VALU + barrier)
    bf16x8 b2r[3][4];
#pragma unroll
    for (int p = 0; p < 3; ++p)
#pragma unroll
        for (int nt = 0; nt < 4; ++nt)
            b2r[p][nt] = *(const bf16x8*)(B2 +
                ((size_t)(((wv * 4 + nt) * 8 + p) * 64 + lane) << 3));

    // epilogue 1: h0 -> tH
    {
        float bv[4];
#pragma unroll
        for (int nt = 0; nt < 4; ++nt)
            bv[nt] = b0[e * HID + wv * 64 + nt * 16 + lr];
#pragma unroll
        for (int mt = 0; mt < 2; ++mt)
#pragma unroll
            for (int rr = 0; rr < 4; ++rr) {
                const int row = mt * 16 + lq * 4 + rr;
#pragma unroll
                for (int nt = 0; nt < 4; ++nt) {
                    const int n = wv * 64 + nt * 16 + lr;
                    float t = tanh_fast(acc[mt][nt][rr] + bv[nt]);
                    tH[(n >> 5) * CH + row * 40 + (n & 31)] = (short)f2bf(t);
                }
            }
    }
    __syncthreads();

    // =============== Stage 2: z1 = h0 @ W1^T   (K=256, ring-3) =============
    ZERO_ACC();
#pragma unroll
    for (int ki = 0; ki < 8; ++ki) {
        bf16x8 af[2];
#pragma unroll
        for (int mt = 0; mt < 2; ++mt)
            af[mt] = *(const bf16x8*)&tH[ki * CH + (mt * 16 + lr) * 40 + lq * 8];
#pragma unroll
        for (int mt = 0; mt < 2; ++mt)
#pragma unroll
            for (int nt = 0; nt < 4; ++nt)
                acc[mt][nt] = __builtin_amdgcn_mfma_f32_16x16x32_bf16(
                    af[mt], b2r[ki % 3][nt], acc[mt][nt], 0, 0, 0);
        if (ki < 5) {
#pragma unroll
            for (int nt = 0; nt < 4; ++nt)
                b2r[ki % 3][nt] = *(const bf16x8*)(B2 +
                    ((size_t)(((wv * 4 + nt) * 8 + ki + 3) * 64 + lane) << 3));
        }
    }

    // S3 B-ring preload (hoisted above epilogue-2 + barrier)
    bf16x8 b3r[3][4];
#pragma unroll
    for (int p = 0; p < 3; ++p)
#pragma unroll
        for (int nt = 0; nt < 4; ++nt)
            b3r[p][nt] = *(const bf16x8*)(B3 +
                ((size_t)(((wv * 4 + nt) * 8 + p) * 64 + lane) << 3));

    // epilogue 2: dz1 -> tD; o partials -> red
    {
        float bv[4], w2v[4];
#pragma unroll
        for (int nt = 0; nt < 4; ++nt) {
            bv[nt]  = b1[e * HID + wv * 64 + nt * 16 + lr];
            w2v[nt] = W2[e * HID + wv * 64 + nt * 16 + lr];
        }
#pragma unroll
        for (int mt = 0; mt < 2; ++mt)
#pragma unroll
            for (int rr = 0; rr < 4; ++rr) {
                const int row = mt * 16 + lq * 4 + rr;
                float osum = 0.f;
#pragma unroll
                for (int nt = 0; nt < 4; ++nt) {
                    const int n = wv * 64 + nt * 16 + lr;
                    float t = tanh_fast(acc[mt][nt][rr] + bv[nt]);
                    osum += t * w2v[nt];
                    tD[(n >> 5) * CH + row * 40 + (n & 31)] =
                        (short)f2bf(w2v[nt] * (1.f - t * t));
                }
                osum += __shfl_xor(osum, 1, 64);
                osum += __shfl_xor(osum, 2, 64);
                osum += __shfl_xor(osum, 4, 64);
                osum += __shfl_xor(osum, 8, 64);
                if (lr == 0) red[wv][row] = osum;
            }
    }
    __syncthreads();
    if (tid < 32) {
        int m = m0 + tid;
        if (m < cnt)
            o_atom[list[m]] = red[0][tid] + red[1][tid] + red[2][tid] +
                              red[3][tid] + b2[e];
    }

    // =============== Stage 3: dh0 = dz1 @ W1   (K=256, ring-3) =============
    ZERO_ACC();
#pragma unroll
    for (int ki = 0; ki < 8; ++ki) {
        bf16x8 af[2];
#pragma unroll
        for (int mt = 0; mt < 2; ++mt)
            af[mt] = *(const bf16x8*)&tD[ki * CH + (mt * 16 + lr) * 40 + lq * 8];
#pragma unroll
        for (int mt = 0; mt < 2; ++mt)
#pragma unroll
            for (int nt = 0; nt < 4; ++nt)
                acc[mt][nt] = __builtin_amdgcn_mfma_f32_16x16x32_bf16(
                    af[mt], b3r[ki % 3][nt], acc[mt][nt], 0, 0, 0);
        if (ki < 5) {
#pragma unroll
            for (int nt = 0; nt < 4; ++nt)
                b3r[ki % 3][nt] = *(const bf16x8*)(B3 +
                    ((size_t)(((wv * 4 + nt) * 8 + ki + 3) * 64 + lane) << 3));
        }
    }

    // S4 B-ring preload (hoisted above epilogue-3 + barrier)
    bf16x8 b4r[3][2];
#pragma unroll
    for (int p = 0; p < 3; ++p)
#pragma unroll
        for (int nt = 0; nt < 2; ++nt)
            b4r[p][nt] = *(const bf16x8*)(B4 +
                ((size_t)(((wv * 2 + nt) * 8 + p) * 64 + lane) << 3));

    // epilogue 3: dz0 = dh0*(1-h0^2) -> tH in-place (same thread owns slot)
#pragma unroll
    for (int mt = 0; mt < 2; ++mt)
#pragma unroll
        for (int rr = 0; rr < 4; ++rr) {
            const int row = mt * 16 + lq * 4 + rr;
#pragma unroll
            for (int nt = 0; nt < 4; ++nt) {
                const int n = wv * 64 + nt * 16 + lr;
                const int a = (n >> 5) * CH + row * 40 + (n & 31);
                float h = bf2f((unsigned short)tH[a]);
                tH[a] = (short)f2bf(acc[mt][nt][rr] * (1.f - h * h));
            }
        }
    __syncthreads();

    // =============== Stage 4: g = dz0 @ W0   (K=256, NT=2, ring-3) =========
    {
        f32x4 a4[2][2];
#pragma unroll
        for (int mt = 0; mt < 2; ++mt)
#pragma unroll
            for (int nt = 0; nt < 2; ++nt)
#pragma unroll
                for (int j = 0; j < 4; ++j) a4[mt][nt][j] = 0.f;
#pragma unroll
        for (int ki = 0; ki < 8; ++ki) {
            bf16x8 af[2];
#pragma unroll
            for (int mt = 0; mt < 2; ++mt)
                af[mt] = *(const bf16x8*)&tH[ki * CH + (mt * 16 + lr) * 40 + lq * 8];
#pragma unroll
            for (int mt = 0; mt < 2; ++mt)
#pragma unroll
                for (int nt = 0; nt < 2; ++nt)
                    a4[mt][nt] = __builtin_amdgcn_mfma_f32_16x16x32_bf16(
                        af[mt], b4r[ki % 3][nt], a4[mt][nt], 0, 0, 0);
            if (ki < 5) {
#pragma unroll
                for (int nt = 0; nt < 2; ++nt)
                    b4r[ki % 3][nt] = *(const bf16x8*)(B4 +
                        ((size_t)(((wv * 2 + nt) * 8 + ki + 3) * 64 + lane) << 3));
            }
        }
        // epilogue 4: g -> tD chunk-major, then coalesced bf16x8 scatter
#pragma unroll
        for (int mt = 0; mt < 2; ++mt)
#pragma unroll
            for (int rr = 0; rr < 4; ++rr) {
                const int row = mt * 16 + lq * 4 + rr;
#pragma unroll
                for (int nt = 0; nt < 2; ++nt) {
                    const int n = wv * 32 + nt * 16 + lr;
                    tD[(n >> 5) * CH + row * 40 + (n & 31)] =
                        (short)f2bf(a4[mt][nt][rr]);
                }
            }
    }
    __syncthreads();
#pragma unroll
    for (int t = 0; t < 2; ++t) {
        const int c = tid + 256 * t;         // 0..511
        const int row = c >> 4;              // 0..31
        const int pos = (c & 15) * 8;        // 0..120
        const int m = m0 + row;
        if (m < cnt) {
            bf16x8 v = *(const bf16x8*)&tD[(pos >> 5) * CH + row * 40 + (pos & 31)];
            *(bf16x8*)(Gb + (size_t)list[m] * IN_DIM + pos) = v;
        }
    }
#undef ZERO_ACC
}

// ---------------------------------------------------------------------------
// K4) Forces consumer — 1024 threads, exclusive col-window in LDS, zero
//     global atomics. Binned entries packed (col9<<23)|row.
//     Blocks < N_IMG also reduce their image's energy.
// ---------------------------------------------------------------------------
__global__ __launch_bounds__(1024) void forces_consumer(
    const unsigned* __restrict__ packB, const float* __restrict__ valsB,
    const int* __restrict__ gcur,
    const unsigned short* __restrict__ g, float* __restrict__ F,
    const float* __restrict__ o_atom, const int* __restrict__ img,
    float* __restrict__ energy,
    const int* __restrict__ ovfR, const int* __restrict__ ovfC,
    const float* __restrict__ ovfV, const int* __restrict__ ocur) {

    const int blk = blockIdx.x;
    __shared__ float win[CW];

    if (blk < CBINS) {
        for (int i = threadIdx.x; i < CW; i += 1024) win[i] = 0.f;
        __syncthreads();
        const int w0 = blk << 9;
        int cnt = gcur[blk]; if (cnt > BCAP) cnt = BCAP;
        const size_t o = (size_t)blk * BCAP;
        for (int idx0 = (int)threadIdx.x * 4; idx0 < cnt; idx0 += 4096) {
            if (idx0 + 4 <= cnt) {
                i32x4 p = *(const i32x4*)((const int*)packB + o + idx0);
                fv4   v = *(const fv4*)(valsB + o + idx0);
                unsigned p0 = (unsigned)p[0], p1 = (unsigned)p[1];
                unsigned p2 = (unsigned)p[2], p3 = (unsigned)p[3];
                float g0 = bf2f(g[p0 & 0x7FFFFFu]), g1 = bf2f(g[p1 & 0x7FFFFFu]);
                float g2 = bf2f(g[p2 & 0x7FFFFFu]), g3 = bf2f(g[p3 & 0x7FFFFFu]);
                atomicAdd(&win[p0 >> 23], -v[0] * g0);
                atomicAdd(&win[p1 >> 23], -v[1] * g1);
                atomicAdd(&win[p2 >> 23], -v[2] * g2);
                atomicAdd(&win[p3 >> 23], -v[3] * g3);
            } else {
                for (int e2 = idx0; e2 < cnt; ++e2) {
                    unsigned p0 = packB[o + e2];
                    atomicAdd(&win[p0 >> 23],
                              -valsB[o + e2] * bf2f(g[p0 & 0x7FFFFFu]));
                }
            }
        }
        // fold overflow entries belonging to this window (expected none)
        int ocnt = ocur[0]; if (ocnt > OCAP) ocnt = OCAP;
        for (int k2 = threadIdx.x; k2 < ocnt; k2 += 1024) {
            int c = ovfC[k2];
            if (c >= w0 && c < w0 + CW)
                atomicAdd(&win[c - w0], -ovfV[k2] * bf2f(g[ovfR[k2]]));
        }
        __syncthreads();
        for (int i = threadIdx.x; i < CW; i += 1024) {
            int c = w0 + i;
            if (c < 3 * N_ATOMS) F[c] = win[i];
        }
    }

    // energy fold
    if (blk < N_IMG) {
        const int bb = blk;
        int lo, hi;
        {
            int l = 0, r = N_ATOMS;
            while (l < r) { int m = (l + r) >> 1; if (img[m] < bb) l = m + 1; else r = m; }
            lo = l;
        }
        {
            int l = lo, r = N_ATOMS;
            while (l < r) { int m = (l + r) >> 1; if (img[m] < bb + 1) l = m + 1; else r = m; }
            hi = l;
        }
        float s = 0.f;
        for (int i2 = lo + (int)threadIdx.x; i2 < hi; i2 += 1024) s += o_atom[i2];
#pragma unroll
        for (int off = 32; off > 0; off >>= 1) s += __shfl_down(s, off, 64);
        __shared__ float red[16];
        if ((threadIdx.x & 63) == 0) red[threadIdx.x >> 6] = s;
        __syncthreads();
        if (threadIdx.x == 0) {
            float t = 0.f;
#pragma unroll
            for (int w = 0; w < 16; ++w) t += red[w];
            energy[bb] = t;
        }
    }
}

// ---------------------------------------------------------------------------
extern "C" void kernel_launch(void* const* d_in, const int* in_sizes, int n_in,
                              void* d_out, int out_size, void* d_ws, size_t ws_size,
                              hipStream_t stream) {
    const float* fp    = (const float*)d_in[0];
    const int*   Z     = (const int*)d_in[1];
    const int*   img   = (const int*)d_in[2];
    const int*   frows = (const int*)d_in[3];
    const int*   fcols = (const int*)d_in[4];
    const float* fvals = (const float*)d_in[5];
    const float* W0    = (const float*)d_in[6];
    const float* b0    = (const float*)d_in[7];
    const float* W1    = (const float*)d_in[8];
    const float* b1    = (const float*)d_in[9];
    const float* W2    = (const float*)d_in[10];
    const float* b2    = (const float*)d_in[11];

    float* out    = (float*)d_out;
    float* energy = out;             // [N_IMG]
    float* F      = out + N_IMG;     // [3*N_ATOMS]

    char* ws = (char*)d_ws;
    int*   counts = (int*)ws;                                   // 16 B
    int*   lists  = (int*)(ws + 1024);                          // 800 KB
    char*  base   = ws + (1 << 20);
    unsigned short* Gb   = (unsigned short*)(base);              // 12.8 MB (atom order)
    float* o_atom        = (float*)(base + 13000000);            // 200 KB
    unsigned short* W0s1 = (unsigned short*)(base + 14000000);   // 256 KB
    unsigned short* W0s4 = W0s1 + N_ELEM * IN_DIM * HID;
    unsigned short* W1s2 = W0s4 + N_ELEM * IN_DIM * HID;
    unsigned short* W1s3 = W1s2 + N_ELEM * HID * HID;
    int*   gcur  = (int*)(base + 18000000);                      // 293 ints
    int*   ocur  = (int*)(base + 18002048);
    unsigned* packB = (unsigned*)(base + 19000000);              // 9.6 MB
    float* valsB = (float*)(base + 29000000);                    // 9.6 MB
    int*   ovfR  = (int*)(base + 49000000);
    int*   ovfC  = (int*)(base + 49050000);
    float* ovfV  = (float*)(base + 49100000);

    // 4 dispatches: prep(+cursors) -> bucket&bin -> fused -> consumer(+energy)
    prep_weights<<<(N_ELEM * HID * HID + 255) / 256, 256, 0, stream>>>(
        W0, W1, W0s1, W1s2, W1s3, W0s4, counts, gcur, ocur);

    bucket_and_bin<<<NBP + BKB, 256, 0, stream>>>(
        Z, counts, lists, F, frows, fcols, fvals,
        packB, valsB, gcur, ovfR, ovfC, ovfV, ocur);

    fused_mlp<<<8 * (TILES_PER_E / 2), 256, 0, stream>>>(
        fp, W0s1, W1s2, W1s3, W0s4, b0, b1, W2, b2, o_atom, Gb, counts, lists);

    forces_consumer<<<N_IMG, 1024, 0, stream>>>(
        packB, valsB, gcur, Gb, F, o_atom, img, energy,
        ovfR, ovfC, ovfV, ocur);
}

// Round 20
// 210.756 us; speedup vs baseline: 1.0833x; 1.0188x over previous
//
#include <hip/hip_runtime.h>
#include <math.h>

#define N_ATOMS 50000
#define IN_DIM 128
#define HID 256
#define N_ELEM 4
#define N_IMG 500
#define NNZ 2000000

// forces col-binning (R14: zero global atomics, consumer owns col-windows)
#define CBINS 293        // col >> 9 over 150,016 cols
#define CW 512           // cols per bin (2 KB LDS window)
#define BCAP 8192        // expect 6826 +- 83 (16 sigma headroom)
#define OCAP 4096        // overflow list capacity (expected use: 0)
#define PCH 8192         // producer chunk (entries per block)
#define NBP ((NNZ + PCH - 1) / PCH)   // 245 producer blocks
#define BKB ((N_ATOMS + 255) / 256)   // 196 bucket blocks

typedef __attribute__((ext_vector_type(8))) short bf16x8;   // 8 bf16 = 4 VGPRs
typedef __attribute__((ext_vector_type(4))) float f32x4;    // MFMA C/D frag
typedef __attribute__((ext_vector_type(4))) int   i32x4;    // native vec loads
typedef __attribute__((ext_vector_type(4))) float fv4;      // native vec loads

__device__ __forceinline__ int elem_of(int z) {
    return (z == 1) ? 0 : (z == 6) ? 1 : (z == 8) ? 2 : 3;
}

__device__ __forceinline__ unsigned short f2bf(float f) {   // RNE
    unsigned u = __float_as_uint(f);
    u += 0x7fffu + ((u >> 16) & 1u);
    return (unsigned short)(u >> 16);
}
__device__ __forceinline__ float bf2f(unsigned short u) {
    return __uint_as_float(((unsigned)u) << 16);
}
__device__ __forceinline__ float tanh_fast(float x) {
    float e = __expf(2.f * x);
    return (e - 1.f) / (e + 1.f);
}

// ---------------------------------------------------------------------------
// K1) Weight prep — pre-swizzle into wave-frag order (R9: worth 44us).
//     Block 0 also zeroes counts + binning cursors (consumed next dispatch).
// ---------------------------------------------------------------------------
__global__ __launch_bounds__(256) void prep_weights(
    const float* __restrict__ W0, const float* __restrict__ W1,
    unsigned short* __restrict__ W0s1,   // stage1: Bt[h][d], K=128, KN=4
    unsigned short* __restrict__ W1s2,   // stage2: Bt[h1][h0], K=256, KN=8
    unsigned short* __restrict__ W1s3,   // stage3: Bt[h0][h1], K=256, KN=8
    unsigned short* __restrict__ W0s4,   // stage4: Bt[d][h], K=256, KN=8
    int* __restrict__ counts, int* __restrict__ gcur, int* __restrict__ ocur) {
    if (blockIdx.x == 0) {
        if (threadIdx.x < N_ELEM) counts[threadIdx.x] = 0;
        for (int i = threadIdx.x; i < CBINS; i += 256) gcur[i] = 0;
        if (threadIdx.x == 0) ocur[0] = 0;
    }
    int t = blockIdx.x * 256 + threadIdx.x;
    if (t >= N_ELEM * HID * HID) return;
    int e = t >> 16;
    int rem = t & 65535;
    int k = rem >> 8, n = rem & 255;     // W1[e][k=h0][n=h1]
    unsigned short w1 = f2bf(W1[t]);
    {   // stage2: row = n (h1), col = k (h0)
        int lane = (((k >> 3) & 3) << 4) | (n & 15);
        W1s2[(e << 16) + ((((n >> 4) * 8 + (k >> 5)) * 64 + lane) << 3) + (k & 7)] = w1;
    }
    {   // stage3: row = k (h0), col = n (h1)
        int lane = (((n >> 3) & 3) << 4) | (k & 15);
        W1s3[(e << 16) + ((((k >> 4) * 8 + (n >> 5)) * 64 + lane) << 3) + (n & 7)] = w1;
    }
    if (k < IN_DIM) {                    // W0[e][d=k][h=n]
        unsigned short w0 = f2bf(W0[e * (IN_DIM * HID) + rem]);
        {   // stage1: row = n (h), col = k (d), K=128 -> KN=4
            int lane = (((k >> 3) & 3) << 4) | (n & 15);
            W0s1[e * (IN_DIM * HID) + ((((n >> 4) * 4 + (k >> 5)) * 64 + lane) << 3) + (k & 7)] = w0;
        }
        {   // stage4: row = k (d), col = n (h), K=256 -> KN=8
            int lane = (((n >> 3) & 3) << 4) | (k & 15);
            W0s4[e * (IN_DIM * HID) + ((((k >> 4) * 8 + (n >> 5)) * 64 + lane) << 3) + (n & 7)] = w0;
        }
    }
}

// ---------------------------------------------------------------------------
// K2) Merged bucket + bin_producer. Binned COO PACKED:
//     entry = (col9 << 23) | row  (row < 6.4M < 2^23, col9 = col & 511).
//     Blocks [0, NBP): COO counting-sort by col-bin (col>>9).
//     Blocks [NBP, NBP+BKB): element bucketing + F zeroing.
// ---------------------------------------------------------------------------
__global__ __launch_bounds__(256) void bucket_and_bin(
    const int* __restrict__ Z, int* __restrict__ counts, int* __restrict__ lists,
    float* __restrict__ F,
    const int* __restrict__ rows, const int* __restrict__ cols,
    const float* __restrict__ vals,
    unsigned* __restrict__ packB, float* __restrict__ valsB,
    int* __restrict__ gcur,
    int* __restrict__ ovfR, int* __restrict__ ovfC, float* __restrict__ ovfV,
    int* __restrict__ ocur) {

    __shared__ int   Lr[PCH];
    __shared__ int   Lc[PCH];
    __shared__ float Lv[PCH];
    __shared__ int   hist[CBINS], pref[CBINS], curs[CBINS], gbase[CBINS];

    const int tid = threadIdx.x;

    if (blockIdx.x >= NBP) {
        // ----- bucket part -----
        int* lcnt = hist;          // reuse LDS
        int* lbase = pref;
        const int bb = blockIdx.x - NBP;
        for (int idx = bb * 256 + tid; idx < 3 * N_ATOMS; idx += BKB * 256)
            F[idx] = 0.f;
        const int i = bb * 256 + tid;
        if (tid < N_ELEM) lcnt[tid] = 0;
        __syncthreads();
        int e = -1, pos = 0;
        if (i < N_ATOMS) {
            e = elem_of(Z[i]);
            pos = atomicAdd(&lcnt[e], 1);
        }
        __syncthreads();
        if (tid < N_ELEM)
            lbase[tid] = atomicAdd(&counts[tid], lcnt[tid]);
        __syncthreads();
        if (i < N_ATOMS) lists[e * N_ATOMS + lbase[e] + pos] = i;
        return;
    }

    // ----- producer part -----
    const int base = blockIdx.x * PCH;

    for (int i = tid; i < CBINS; i += 256) hist[i] = 0;
    __syncthreads();

    // phase 1: stash 32 entries (8 x int4 groups, coalesced) + LDS histogram
    i32x4 r[8], c[8];
    fv4   v[8];
    int nvalid[8];
#pragma unroll
    for (int j = 0; j < 8; ++j) {
        const int i0 = base + tid * 4 + 1024 * j;
        int nv = NNZ - i0;
        nvalid[j] = nv > 4 ? 4 : (nv < 0 ? 0 : nv);
        if (nvalid[j] == 4) {
            r[j] = __builtin_nontemporal_load((const i32x4*)(rows + i0));
            c[j] = __builtin_nontemporal_load((const i32x4*)(cols + i0));
            v[j] = __builtin_nontemporal_load((const fv4*)(vals + i0));
        } else {
            for (int e2 = 0; e2 < nvalid[j]; ++e2) {
                r[j][e2] = rows[i0 + e2]; c[j][e2] = cols[i0 + e2];
                v[j][e2] = vals[i0 + e2];
            }
        }
#pragma unroll
        for (int e2 = 0; e2 < 4; ++e2)
            if (e2 < nvalid[j]) atomicAdd(&hist[c[j][e2] >> 9], 1);
    }
    __syncthreads();

    // phase 2: serial prefix (293 tiny) by thread 0
    if (tid == 0) {
        int s = 0;
        for (int b = 0; b < CBINS; ++b) { pref[b] = s; s += hist[b]; }
    }
    __syncthreads();
    // phase 2.5: reserve global ranges; init cursors
    for (int b = tid; b < CBINS; b += 256) {
        gbase[b] = atomicAdd(&gcur[b], hist[b]);
        curs[b] = pref[b];
    }
    __syncthreads();

    // phase 3: scatter into LDS (counting-sort order)
#pragma unroll
    for (int j = 0; j < 8; ++j)
#pragma unroll
        for (int e2 = 0; e2 < 4; ++e2)
            if (e2 < nvalid[j]) {
                int b = c[j][e2] >> 9;
                int p = atomicAdd(&curs[b], 1);
                Lr[p] = r[j][e2]; Lc[p] = c[j][e2]; Lv[p] = v[j][e2];
            }
    __syncthreads();

    // phase 4: linear LDS -> global, packed (runs per bin = coalesced)
    const int total = (base + PCH <= NNZ) ? PCH : (NNZ - base);
#pragma unroll
    for (int j = 0; j < 32; ++j) {
        const int p = tid + 256 * j;
        if (p >= total) break;
        const int col = Lc[p];
        const int b = col >> 9;
        const int g = gbase[b] + (p - pref[b]);
        if (g < BCAP) {
            packB[b * BCAP + g] = ((unsigned)(col & 511) << 23) | (unsigned)Lr[p];
            valsB[b * BCAP + g] = Lv[p];
        } else {
            int od = atomicAdd(ocur, 1);
            if (od < OCAP) { ovfR[od] = Lr[p]; ovfC[od] = col; ovfV[od] = Lv[p]; }
        }
    }
}

// ---------------------------------------------------------------------------
// K3) FULLY-FUSED MLP fwd+bwd — R19 post-mortem: S1's per-ki A-frag loads
//     were 16-way FRAGMENTED (16 gathered rows per wave load inst -> ~1.6M
//     txns, the R8 lesson hiding on the A side). Now: stage the 32x128 fp
//     tile ONCE with row-contiguous 32-lane loads (~128 txns/block, 12x
//     fewer) into the tD buffer (idle until epilogue-2), convert to bf16,
//     then S1 reads frags from LDS like every other stage. Also deletes the
//     A-ring registers. Config stays R17/R19 measured-best: M=32, stride
//     40, 3 blocks/CU, swizzled B + ring prefetch, barrier-free K-loops.
// ---------------------------------------------------------------------------
#define TILES_PER_E 512   // 32-row tiles
#define CH 1280           // chunk stride in shorts (32*40)
__global__ __launch_bounds__(256, 3) void fused_mlp(
    const float* __restrict__ fp,
    const unsigned short* __restrict__ W0s1,
    const unsigned short* __restrict__ W1s2,
    const unsigned short* __restrict__ W1s3,
    const unsigned short* __restrict__ W0s4,
    const float* __restrict__ b0, const float* __restrict__ b1,
    const float* __restrict__ W2, const float* __restrict__ b2,
    float* __restrict__ o_atom,
    unsigned short* __restrict__ Gb,
    const int* __restrict__ counts, const int* __restrict__ lists) {

    const int bid = blockIdx.x;
    const int xcd = bid & 7;
    const int e = xcd & 3;                       // element pinned to XCD pair
    const int tile = (bid >> 3) * 2 + (xcd >> 2);
    const int cnt = counts[e];
    const int m0 = tile * 32;
    if (m0 >= cnt) return;
    const int* list = lists + e * N_ATOMS;

    __shared__ short tH[8 * CH];           // 20480 B
    __shared__ short tD[8 * CH];           // 20480 B (S1: A-tile staging)
    __shared__ float red[4][32];           // 512 B   (total 41.5 KB)

    const int tid = threadIdx.x;
    const int lane = tid & 63;
    const int wv = tid >> 6;       // 0..3, n-range wv*64
    const int lr = lane & 15;
    const int lq = lane >> 4;

    const unsigned short* B1 = W0s1 + (size_t)e * HID * IN_DIM;
    const unsigned short* B2 = W1s2 + (size_t)e * HID * HID;
    const unsigned short* B3 = W1s3 + (size_t)e * HID * HID;
    const unsigned short* B4 = W0s4 + (size_t)e * IN_DIM * HID;

    f32x4 acc[2][4];
#define ZERO_ACC()                                                        \
    _Pragma("unroll") for (int mt = 0; mt < 2; ++mt)                      \
        _Pragma("unroll") for (int nt = 0; nt < 4; ++nt)                  \
            _Pragma("unroll") for (int j = 0; j < 4; ++j) acc[mt][nt][j] = 0.f;

    // ---- S1 A-tile staging: 4 passes, 32-lane groups read a full gathered
    //      row CONTIGUOUSLY (4 lines/row); bf16 -> tD chunk-major.
    {
        bf16x8 bb0[4];   // hoisted B ki=0 preload (flies during staging)
#pragma unroll
        for (int nt = 0; nt < 4; ++nt)
            bb0[nt] = *(const bf16x8*)(B1 +
                ((size_t)(((wv * 4 + nt) * 4 + 0) * 64 + lane) << 3));

#pragma unroll
        for (int p = 0; p < 4; ++p) {
            const int row = p * 8 + (tid >> 5);
            const int col = (tid & 31) * 4;          // float index in row
            const int m = m0 + row;
            float4 a = make_float4(0.f, 0.f, 0.f, 0.f);
            if (m < cnt)
                a = *(const float4*)(fp + (size_t)list[m] * IN_DIM + col);
            short4 b;
            b.x = (short)f2bf(a.x); b.y = (short)f2bf(a.y);
            b.z = (short)f2bf(a.z); b.w = (short)f2bf(a.w);
            *(short4*)&tD[(col >> 5) * CH + row * 40 + (col & 31)] = b;
        }
        __syncthreads();

        // =============== Stage 1: z0 = A @ W0^T  (K=128, KN=4, B ring-2) ===
        ZERO_ACC();
        bf16x8 bb[2][4];
#pragma unroll
        for (int nt = 0; nt < 4; ++nt) bb[0][nt] = bb0[nt];
#pragma unroll
        for (int ki = 0; ki < 4; ++ki) {
            const int cur = ki & 1, nx = cur ^ 1;
            if (ki < 3) {
#pragma unroll
                for (int nt = 0; nt < 4; ++nt)
                    bb[nx][nt] = *(const bf16x8*)(B1 +
                        ((size_t)(((wv * 4 + nt) * 4 + ki + 1) * 64 + lane) << 3));
            }
            bf16x8 af[2];
#pragma unroll
            for (int mt = 0; mt < 2; ++mt)
                af[mt] = *(const bf16x8*)&tD[ki * CH + (mt * 16 + lr) * 40 + lq * 8];
#pragma unroll
            for (int mt = 0; mt < 2; ++mt)
#pragma unroll
                for (int nt = 0; nt < 4; ++nt)
                    acc[mt][nt] = __builtin_amdgcn_mfma_f32_16x16x32_bf16(
                        af[mt], bb[cur][nt], acc[mt][nt], 0, 0, 0);
        }
    }

    // S2 B-ring preload (hoisted: flies during epilogue-1 VALU + barrier)
    bf16x8 b2r[3][4];
#pragma unroll
    for (int p = 0; p < 3; ++p)
#pragma unroll
        for (int nt = 0; nt < 4; ++nt)
            b2r[p][nt] = *(const bf16x8*)(B2 +
                ((size_t)(((wv * 4 + nt) * 8 + p) * 64 + lane) << 3));

    // epilogue 1: h0 -> tH   (barrier first: tD still being read by S1 above
    //   is fine — all reads done; but tH writes race nothing. The existing
    //   post-epilogue barrier covers tH visibility for S2.)
    {
        float bv[4];
#pragma unroll
        for (int nt = 0; nt < 4; ++nt)
            bv[nt] = b0[e * HID + wv * 64 + nt * 16 + lr];
#pragma unroll
        for (int mt = 0; mt < 2; ++mt)
#pragma unroll
            for (int rr = 0; rr < 4; ++rr) {
                const int row = mt * 16 + lq * 4 + rr;
#pragma unroll
                for (int nt = 0; nt < 4; ++nt) {
                    const int n = wv * 64 + nt * 16 + lr;
                    float t = tanh_fast(acc[mt][nt][rr] + bv[nt]);
                    tH[(n >> 5) * CH + row * 40 + (n & 31)] = (short)f2bf(t);
                }
            }
    }
    __syncthreads();

    // =============== Stage 2: z1 = h0 @ W1^T   (K=256, ring-3) =============
    ZERO_ACC();
#pragma unroll
    for (int ki = 0; ki < 8; ++ki) {
        bf16x8 af[2];
#pragma unroll
        for (int mt = 0; mt < 2; ++mt)
            af[mt] = *(const bf16x8*)&tH[ki * CH + (mt * 16 + lr) * 40 + lq * 8];
#pragma unroll
        for (int mt = 0; mt < 2; ++mt)
#pragma unroll
            for (int nt = 0; nt < 4; ++nt)
                acc[mt][nt] = __builtin_amdgcn_mfma_f32_16x16x32_bf16(
                    af[mt], b2r[ki % 3][nt], acc[mt][nt], 0, 0, 0);
        if (ki < 5) {
#pragma unroll
            for (int nt = 0; nt < 4; ++nt)
                b2r[ki % 3][nt] = *(const bf16x8*)(B2 +
                    ((size_t)(((wv * 4 + nt) * 8 + ki + 3) * 64 + lane) << 3));
        }
    }

    // S3 B-ring preload (hoisted above epilogue-2 + barrier)
    bf16x8 b3r[3][4];
#pragma unroll
    for (int p = 0; p < 3; ++p)
#pragma unroll
        for (int nt = 0; nt < 4; ++nt)
            b3r[p][nt] = *(const bf16x8*)(B3 +
                ((size_t)(((wv * 4 + nt) * 8 + p) * 64 + lane) << 3));

    // epilogue 2: dz1 -> tD; o partials -> red
    {
        float bv[4], w2v[4];
#pragma unroll
        for (int nt = 0; nt < 4; ++nt) {
            bv[nt]  = b1[e * HID + wv * 64 + nt * 16 + lr];
            w2v[nt] = W2[e * HID + wv * 64 + nt * 16 + lr];
        }
#pragma unroll
        for (int mt = 0; mt < 2; ++mt)
#pragma unroll
            for (int rr = 0; rr < 4; ++rr) {
                const int row = mt * 16 + lq * 4 + rr;
                float osum = 0.f;
#pragma unroll
                for (int nt = 0; nt < 4; ++nt) {
                    const int n = wv * 64 + nt * 16 + lr;
                    float t = tanh_fast(acc[mt][nt][rr] + bv[nt]);
                    osum += t * w2v[nt];
                    tD[(n >> 5) * CH + row * 40 + (n & 31)] =
                        (short)f2bf(w2v[nt] * (1.f - t * t));
                }
                osum += __shfl_xor(osum, 1, 64);
                osum += __shfl_xor(osum, 2, 64);
                osum += __shfl_xor(osum, 4, 64);
                osum += __shfl_xor(osum, 8, 64);
                if (lr == 0) red[wv][row] = osum;
            }
    }
    __syncthreads();
    if (tid < 32) {
        int m = m0 + tid;
        if (m < cnt)
            o_atom[list[m]] = red[0][tid] + red[1][tid] + red[2][tid] +
                              red[3][tid] + b2[e];
    }

    // =============== Stage 3: dh0 = dz1 @ W1   (K=256, ring-3) =============
    ZERO_ACC();
#pragma unroll
    for (int ki = 0; ki < 8; ++ki) {
        bf16x8 af[2];
#pragma unroll
        for (int mt = 0; mt < 2; ++mt)
            af[mt] = *(const bf16x8*)&tD[ki * CH + (mt * 16 + lr) * 40 + lq * 8];
#pragma unroll
        for (int mt = 0; mt < 2; ++mt)
#pragma unroll
            for (int nt = 0; nt < 4; ++nt)
                acc[mt][nt] = __builtin_amdgcn_mfma_f32_16x16x32_bf16(
                    af[mt], b3r[ki % 3][nt], acc[mt][nt], 0, 0, 0);
        if (ki < 5) {
#pragma unroll
            for (int nt = 0; nt < 4; ++nt)
                b3r[ki % 3][nt] = *(const bf16x8*)(B3 +
                    ((size_t)(((wv * 4 + nt) * 8 + ki + 3) * 64 + lane) << 3));
        }
    }

    // S4 B-ring preload (hoisted above epilogue-3 + barrier)
    bf16x8 b4r[3][2];
#pragma unroll
    for (int p = 0; p < 3; ++p)
#pragma unroll
        for (int nt = 0; nt < 2; ++nt)
            b4r[p][nt] = *(const bf16x8*)(B4 +
                ((size_t)(((wv * 2 + nt) * 8 + p) * 64 + lane) << 3));

    // epilogue 3: dz0 = dh0*(1-h0^2) -> tH in-place (same thread owns slot)
#pragma unroll
    for (int mt = 0; mt < 2; ++mt)
#pragma unroll
        for (int rr = 0; rr < 4; ++rr) {
            const int row = mt * 16 + lq * 4 + rr;
#pragma unroll
            for (int nt = 0; nt < 4; ++nt) {
                const int n = wv * 64 + nt * 16 + lr;
                const int a = (n >> 5) * CH + row * 40 + (n & 31);
                float h = bf2f((unsigned short)tH[a]);
                tH[a] = (short)f2bf(acc[mt][nt][rr] * (1.f - h * h));
            }
        }
    __syncthreads();

    // =============== Stage 4: g = dz0 @ W0   (K=256, NT=2, ring-3) =========
    {
        f32x4 a4[2][2];
#pragma unroll
        for (int mt = 0; mt < 2; ++mt)
#pragma unroll
            for (int nt = 0; nt < 2; ++nt)
#pragma unroll
                for (int j = 0; j < 4; ++j) a4[mt][nt][j] = 0.f;
#pragma unroll
        for (int ki = 0; ki < 8; ++ki) {
            bf16x8 af[2];
#pragma unroll
            for (int mt = 0; mt < 2; ++mt)
                af[mt] = *(const bf16x8*)&tH[ki * CH + (mt * 16 + lr) * 40 + lq * 8];
#pragma unroll
            for (int mt = 0; mt < 2; ++mt)
#pragma unroll
                for (int nt = 0; nt < 2; ++nt)
                    a4[mt][nt] = __builtin_amdgcn_mfma_f32_16x16x32_bf16(
                        af[mt], b4r[ki % 3][nt], a4[mt][nt], 0, 0, 0);
            if (ki < 5) {
#pragma unroll
                for (int nt = 0; nt < 2; ++nt)
                    b4r[ki % 3][nt] = *(const bf16x8*)(B4 +
                        ((size_t)(((wv * 2 + nt) * 8 + ki + 3) * 64 + lane) << 3));
            }
        }
        // epilogue 4: g -> tD chunk-major, then coalesced bf16x8 scatter
#pragma unroll
        for (int mt = 0; mt < 2; ++mt)
#pragma unroll
            for (int rr = 0; rr < 4; ++rr) {
                const int row = mt * 16 + lq * 4 + rr;
#pragma unroll
                for (int nt = 0; nt < 2; ++nt) {
                    const int n = wv * 32 + nt * 16 + lr;
                    tD[(n >> 5) * CH + row * 40 + (n & 31)] =
                        (short)f2bf(a4[mt][nt][rr]);
                }
            }
    }
    __syncthreads();
#pragma unroll
    for (int t = 0; t < 2; ++t) {
        const int c = tid + 256 * t;         // 0..511
        const int row = c >> 4;              // 0..31
        const int pos = (c & 15) * 8;        // 0..120
        const int m = m0 + row;
        if (m < cnt) {
            bf16x8 v = *(const bf16x8*)&tD[(pos >> 5) * CH + row * 40 + (pos & 31)];
            *(bf16x8*)(Gb + (size_t)list[m] * IN_DIM + pos) = v;
        }
    }
#undef ZERO_ACC
}

// ---------------------------------------------------------------------------
// K4) Forces consumer — 1024 threads, exclusive col-window in LDS, zero
//     global atomics. Binned entries packed (col9<<23)|row.
//     Blocks < N_IMG also reduce their image's energy.
// ---------------------------------------------------------------------------
__global__ __launch_bounds__(1024) void forces_consumer(
    const unsigned* __restrict__ packB, const float* __restrict__ valsB,
    const int* __restrict__ gcur,
    const unsigned short* __restrict__ g, float* __restrict__ F,
    const float* __restrict__ o_atom, const int* __restrict__ img,
    float* __restrict__ energy,
    const int* __restrict__ ovfR, const int* __restrict__ ovfC,
    const float* __restrict__ ovfV, const int* __restrict__ ocur) {

    const int blk = blockIdx.x;
    __shared__ float win[CW];

    if (blk < CBINS) {
        for (int i = threadIdx.x; i < CW; i += 1024) win[i] = 0.f;
        __syncthreads();
        const int w0 = blk << 9;
        int cnt = gcur[blk]; if (cnt > BCAP) cnt = BCAP;
        const size_t o = (size_t)blk * BCAP;
        for (int idx0 = (int)threadIdx.x * 4; idx0 < cnt; idx0 += 4096) {
            if (idx0 + 4 <= cnt) {
                i32x4 p = *(const i32x4*)((const int*)packB + o + idx0);
                fv4   v = *(const fv4*)(valsB + o + idx0);
                unsigned p0 = (unsigned)p[0], p1 = (unsigned)p[1];
                unsigned p2 = (unsigned)p[2], p3 = (unsigned)p[3];
                float g0 = bf2f(g[p0 & 0x7FFFFFu]), g1 = bf2f(g[p1 & 0x7FFFFFu]);
                float g2 = bf2f(g[p2 & 0x7FFFFFu]), g3 = bf2f(g[p3 & 0x7FFFFFu]);
                atomicAdd(&win[p0 >> 23], -v[0] * g0);
                atomicAdd(&win[p1 >> 23], -v[1] * g1);
                atomicAdd(&win[p2 >> 23], -v[2] * g2);
                atomicAdd(&win[p3 >> 23], -v[3] * g3);
            } else {
                for (int e2 = idx0; e2 < cnt; ++e2) {
                    unsigned p0 = packB[o + e2];
                    atomicAdd(&win[p0 >> 23],
                              -valsB[o + e2] * bf2f(g[p0 & 0x7FFFFFu]));
                }
            }
        }
        // fold overflow entries belonging to this window (expected none)
        int ocnt = ocur[0]; if (ocnt > OCAP) ocnt = OCAP;
        for (int k2 = threadIdx.x; k2 < ocnt; k2 += 1024) {
            int c = ovfC[k2];
            if (c >= w0 && c < w0 + CW)
                atomicAdd(&win[c - w0], -ovfV[k2] * bf2f(g[ovfR[k2]]));
        }
        __syncthreads();
        for (int i = threadIdx.x; i < CW; i += 1024) {
            int c = w0 + i;
            if (c < 3 * N_ATOMS) F[c] = win[i];
        }
    }

    // energy fold
    if (blk < N_IMG) {
        const int bb = blk;
        int lo, hi;
        {
            int l = 0, r = N_ATOMS;
            while (l < r) { int m = (l + r) >> 1; if (img[m] < bb) l = m + 1; else r = m; }
            lo = l;
        }
        {
            int l = lo, r = N_ATOMS;
            while (l < r) { int m = (l + r) >> 1; if (img[m] < bb + 1) l = m + 1; else r = m; }
            hi = l;
        }
        float s = 0.f;
        for (int i2 = lo + (int)threadIdx.x; i2 < hi; i2 += 1024) s += o_atom[i2];
#pragma unroll
        for (int off = 32; off > 0; off >>= 1) s += __shfl_down(s, off, 64);
        __shared__ float red[16];
        if ((threadIdx.x & 63) == 0) red[threadIdx.x >> 6] = s;
        __syncthreads();
        if (threadIdx.x == 0) {
            float t = 0.f;
#pragma unroll
            for (int w = 0; w < 16; ++w) t += red[w];
            energy[bb] = t;
        }
    }
}

// ---------------------------------------------------------------------------
extern "C" void kernel_launch(void* const* d_in, const int* in_sizes, int n_in,
                              void* d_out, int out_size, void* d_ws, size_t ws_size,
                              hipStream_t stream) {
    const float* fp    = (const float*)d_in[0];
    const int*   Z     = (const int*)d_in[1];
    const int*   img   = (const int*)d_in[2];
    const int*   frows = (const int*)d_in[3];
    const int*   fcols = (const int*)d_in[4];
    const float* fvals = (const float*)d_in[5];
    const float* W0    = (const float*)d_in[6];
    const float* b0    = (const float*)d_in[7];
    const float* W1    = (const float*)d_in[8];
    const float* b1    = (const float*)d_in[9];
    const float* W2    = (const float*)d_in[10];
    const float* b2    = (const float*)d_in[11];

    float* out    = (float*)d_out;
    float* energy = out;             // [N_IMG]
    float* F      = out + N_IMG;     // [3*N_ATOMS]

    char* ws = (char*)d_ws;
    int*   counts = (int*)ws;                                   // 16 B
    int*   lists  = (int*)(ws + 1024);                          // 800 KB
    char*  base   = ws + (1 << 20);
    unsigned short* Gb   = (unsigned short*)(base);              // 12.8 MB (atom order)
    float* o_atom        = (float*)(base + 13000000);            // 200 KB
    unsigned short* W0s1 = (unsigned short*)(base + 14000000);   // 256 KB
    unsigned short* W0s4 = W0s1 + N_ELEM * IN_DIM * HID;
    unsigned short* W1s2 = W0s4 + N_ELEM * IN_DIM * HID;
    unsigned short* W1s3 = W1s2 + N_ELEM * HID * HID;
    int*   gcur  = (int*)(base + 18000000);                      // 293 ints
    int*   ocur  = (int*)(base + 18002048);
    unsigned* packB = (unsigned*)(base + 19000000);              // 9.6 MB
    float* valsB = (float*)(base + 29000000);                    // 9.6 MB
    int*   ovfR  = (int*)(base + 49000000);
    int*   ovfC  = (int*)(base + 49050000);
    float* ovfV  = (float*)(base + 49100000);

    // 4 dispatches: prep(+cursors) -> bucket&bin -> fused -> consumer(+energy)
    prep_weights<<<(N_ELEM * HID * HID + 255) / 256, 256, 0, stream>>>(
        W0, W1, W0s1, W1s2, W1s3, W0s4, counts, gcur, ocur);

    bucket_and_bin<<<NBP + BKB, 256, 0, stream>>>(
        Z, counts, lists, F, frows, fcols, fvals,
        packB, valsB, gcur, ovfR, ovfC, ovfV, ocur);

    fused_mlp<<<8 * (TILES_PER_E / 2), 256, 0, stream>>>(
        fp, W0s1, W1s2, W1s3, W0s4, b0, b1, W2, b2, o_atom, Gb, counts, lists);

    forces_consumer<<<N_IMG, 1024, 0, stream>>>(
        packB, valsB, gcur, Gb, F, o_atom, img, energy,
        ovfR, ovfC, ovfV, ocur);
}